// Round 4
// baseline (386.676 us; speedup 1.0000x reference)
//
#include <hip/hip_runtime.h>
#include <math.h>
#include <stdint.h>

// Problem constants
#define BB    8
#define DIN   1024
#define TT    2048
#define KK    8192
#define DCB   8
#define NPOS  (BB*TT)         // 16384
#define KCHUNKS 64
#define KCH     (KK/KCHUNKS)  // 128
#define MARGIN  6e-4f         // >= 2*eps_bf16_screen(1.2e-4) + pack quant(6e-5), 2x headroom

// d_out layout (float32):
#define OFF_ZQOUT  0
#define OFF_COMMIT 16777216
#define OFF_CBLOSS 16777224
#define OFF_IDX    16777232
#define OFF_ZE     16793616

typedef short s8v __attribute__((ext_vector_type(8)));   // 8 bf16 in 4 VGPRs
typedef float f4v __attribute__((ext_vector_type(4)));

__device__ __forceinline__ unsigned short f2bf(float f) {
    unsigned u = __float_as_uint(f);
    u += 0x7FFF + ((u >> 16) & 1);          // round-to-nearest-even
    return (unsigned short)(u >> 16);
}
__device__ __forceinline__ float bf2f(unsigned short h) {
    return __uint_as_float(((unsigned)h) << 16);
}

// ---------------- kernel 1: prep (44 blocks, parallel roles) ----------------
// blocks 0..7: w_in rows (fp64); 8..11: w_out (fp32); 12..43: codebook
// (fp64 normalize + bf16 hi/lo mirror + skp).
__global__ __launch_bounds__(256) void k_prep(
    const float* __restrict__ in_v, const float* __restrict__ in_g,
    const float* __restrict__ out_v, const float* __restrict__ out_g,
    const float* __restrict__ cb,
    double* __restrict__ w_in_d, float* __restrict__ w_out_f,
    double* __restrict__ cb_n, double* __restrict__ s_k,
    unsigned short* __restrict__ cb16, float* __restrict__ skp_f,
    double* __restrict__ lossS)
{
    __shared__ double red[256];
    int tid = threadIdx.x;
    int blk = blockIdx.x;
    if (blk == 0 && tid < 16) lossS[tid] = 0.0;

    if (blk < 8) {
        int r = blk;
        double s = 0.0;
        for (int i = tid; i < DIN; i += 256) {
            double v = (double)in_v[r*DIN + i];
            s += v*v;
        }
        red[tid] = s; __syncthreads();
        for (int off = 128; off > 0; off >>= 1) {
            if (tid < off) red[tid] += red[tid+off];
            __syncthreads();
        }
        double scale = (double)in_g[r] / sqrt(red[0]);
        for (int i = tid; i < DIN; i += 256)
            w_in_d[r*DIN + i] = scale * (double)in_v[r*DIN + i];
    } else if (blk < 12) {
        int o = (blk-8)*256 + tid;
        float vv[DCB];
        double s = 0.0;
        #pragma unroll
        for (int d = 0; d < DCB; ++d) {
            vv[d] = out_v[o*DCB + d];
            s += (double)vv[d]*(double)vv[d];
        }
        double scale = (double)out_g[o] / sqrt(s);
        #pragma unroll
        for (int d = 0; d < DCB; ++d)
            w_out_f[o*DCB + d] = (float)(scale * (double)vv[d]);
    } else {
        int k = (blk-12)*256 + tid;
        double v[DCB]; double s = 0.0;
        #pragma unroll
        for (int d = 0; d < DCB; ++d) {
            v[d] = (double)cb[k*DCB + d];
            s += v[d]*v[d];
        }
        double nrm = sqrt(s);
        if (nrm < 1e-12) nrm = 1e-12;
        double s2 = 0.0;
        #pragma unroll
        for (int d = 0; d < DCB; ++d) {
            double t = v[d] / nrm;
            cb_n[(size_t)k*DCB + d] = t;
            s2 += t*t;
            float cf = (float)t;
            unsigned short bh = f2bf(cf);
            unsigned short bl = f2bf(cf - bf2f(bh));
            cb16[(size_t)k*16 + d]     = bh;
            cb16[(size_t)k*16 + 8 + d] = bl;
        }
        s_k[k] = s2;
        skp_f[k] = (float)(s2 + 4.0);   // shift => dist' = skp - 2*dot in [3,7] > 0
    }
}

// ---------------- kernel 2: fused in-projection + reduce (fp64) -------------
// Summation order identical to R1..R3 (passed) => bit-identical z_e/enc_n/q_s.
__global__ __launch_bounds__(256) void k_inproj(
    const float* __restrict__ z, const double* __restrict__ w_in_d,
    const float* __restrict__ in_b,
    float* __restrict__ ze_out, double* __restrict__ enc_n,
    double* __restrict__ q_s, unsigned short* __restrict__ enc16)
{
    __shared__ double wl[DIN*DCB];   // 64 KB
    __shared__ double red[2048];     // 16 KB

    int tid = threadIdx.x;
    for (int x = tid; x < DIN*DCB; x += 256) wl[x] = w_in_d[x];
    __syncthreads();

    int p = tid & 31;
    int q = tid >> 5;
    int pos = blockIdx.x*32 + p;
    int b = pos >> 11, t = pos & (TT-1);

    const float* zp = z + ((size_t)b*DIN + (size_t)q*128)*TT + t;
    double acc[DCB] = {0,0,0,0,0,0,0,0};
    for (int ii = 0; ii < 128; ++ii) {
        double zv = (double)zp[(size_t)ii*TT];
        int wbase = q*128 + ii;
        #pragma unroll
        for (int o = 0; o < DCB; ++o) acc[o] += wl[o*DIN + wbase] * zv;
    }
    #pragma unroll
    for (int o = 0; o < DCB; ++o) red[(q*32 + p)*DCB + o] = acc[o];
    __syncthreads();

    int p2 = tid >> 3, o2 = tid & 7;
    double s = 0.0;
    for (int q2 = 0; q2 < 8; ++q2) s += red[(q2*32 + p2)*DCB + o2];
    s += (double)in_b[o2];
    __syncthreads();
    red[p2*DCB + o2] = s;
    __syncthreads();

    if (tid < 32) {
        int pos3 = blockIdx.x*32 + tid;
        int b3 = pos3 >> 11, t3 = pos3 & (TT-1);
        double v[DCB]; double n2 = 0.0;
        #pragma unroll
        for (int o = 0; o < DCB; ++o) {
            v[o] = red[tid*DCB + o];
            n2 += v[o]*v[o];
            ze_out[((size_t)b3*DCB + o)*TT + t3] = (float)v[o];
        }
        double nrm = sqrt(n2);
        if (nrm < 1e-12) nrm = 1e-12;
        double s2 = 0.0;
        #pragma unroll
        for (int o = 0; o < DCB; ++o) {
            double e = v[o] / nrm;
            enc_n[(size_t)pos3*DCB + o] = e;
            s2 += e*e;
            float ef = (float)(-2.0 * e);      // A operand = -2*enc_n
            unsigned short ah = f2bf(ef);
            unsigned short al = f2bf(ef - bf2f(ah));
            enc16[(size_t)pos3*16 + o]     = ah;
            enc16[(size_t)pos3*16 + 8 + o] = al;
        }
        q_s[pos3] = s2;
    }
}

// ---------------- kernel 3: MFMA bf16 hi/lo argmin screen --------------------
// grid (256 q-blocks of 64, 8 chunk-groups of 8). One mfma_f32_16x16x32_bf16
// per 16q x 16n tile: K packed as A=[ah,al,ah,0] x B=[bh,bh,bl,*]
// => ah*bh + al*bh + ah*bl (al*bl + residuals bounded by 1.2e-4).
// skp (fp32-exact) enters via accumulator init. d1-only per chunk.
#define SCR_QB 64
#define SCR_CB 8
__global__ __launch_bounds__(256) void k_screen(
    const unsigned short* __restrict__ enc16,
    const unsigned short* __restrict__ cb16,
    const float* __restrict__ skp_f,
    int* __restrict__ d1key)   // [q][KCHUNKS]
{
    __shared__ unsigned short cbl[SCR_CB*KCH*16];  // 32 KB
    __shared__ float skl[SCR_CB*KCH];              // 4 KB
    int tid = threadIdx.x;
    int cg = blockIdx.y;

    {   // stage 8 chunks of codebook bf16 + skp
        const uint4* src = (const uint4*)(cb16 + (size_t)cg*SCR_CB*KCH*16);
        uint4* dst = (uint4*)cbl;
        for (int x = tid; x < SCR_CB*KCH*2; x += 256) dst[x] = src[x];
        const float* ss = skp_f + cg*SCR_CB*KCH;
        for (int x = tid; x < SCR_CB*KCH; x += 256) skl[x] = ss[x];
    }
    __syncthreads();

    int lane = tid & 63;
    int wv   = tid >> 6;
    int col  = lane & 15, quad = lane >> 4;
    int qbase = blockIdx.x*SCR_QB + wv*16;

    // A fragment: lane holds A[m=col][k=quad*8+j]; quad 0,2 -> ah, 1 -> al, 3 -> 0
    s8v a;
    {
        const s8v* ap = (const s8v*)(enc16 + ((size_t)(qbase + col))*16 + (quad==1 ? 8 : 0));
        a = *ap;
        if (quad == 3) { s8v zz = {0,0,0,0,0,0,0,0}; a = zz; }
    }
    int bsel = (quad == 2) ? 1 : 0;   // B: quad 0,1 -> bh, 2 -> bl, 3 -> bh (A=0 there)

    for (int c2 = 0; c2 < SCR_CB; ++c2) {
        int d0 = 0x7F800000, d1r = 0x7F800000, d2r = 0x7F800000, d3r = 0x7F800000;
        const s8v* bp = (const s8v*)(cbl + c2*KCH*16);
        const float* sp = skl + c2*KCH;
        #pragma unroll
        for (int t = 0; t < 8; ++t) {
            int n = t*16 + col;
            s8v bfr = bp[n*2 + bsel];
            float sk = sp[n];
            f4v acc = {sk, sk, sk, sk};
            acc = __builtin_amdgcn_mfma_f32_16x16x32_bf16(a, bfr, acc, 0, 0, 0);
            // C layout: col = lane&15 (n), row = quad*4 + reg  -> pack 7-bit n
            d0  = min(d0,  (int)((__float_as_uint(acc.x) & 0xFFFFFF80u) | (unsigned)n));
            d1r = min(d1r, (int)((__float_as_uint(acc.y) & 0xFFFFFF80u) | (unsigned)n));
            d2r = min(d2r, (int)((__float_as_uint(acc.z) & 0xFFFFFF80u) | (unsigned)n));
            d3r = min(d3r, (int)((__float_as_uint(acc.w) & 0xFFFFFF80u) | (unsigned)n));
        }
        // reduce over the 16 n-columns (lanes differing in low 4 bits)
        #pragma unroll
        for (int off = 1; off < 16; off <<= 1) {
            d0  = min(d0,  __shfl_xor(d0,  off, 64));
            d1r = min(d1r, __shfl_xor(d1r, off, 64));
            d2r = min(d2r, __shfl_xor(d2r, off, 64));
            d3r = min(d3r, __shfl_xor(d3r, off, 64));
        }
        if (col == 0) {
            int chunk = cg*SCR_CB + c2;
            int qrow  = qbase + quad*4;
            int* dst = d1key + (size_t)qrow*KCHUNKS + chunk;
            dst[0*KCHUNKS] = d0;
            dst[1*KCHUNKS] = d1r;
            dst[2*KCHUNKS] = d2r;
            dst[3*KCHUNKS] = d3r;
        }
    }
}

// ---------------- kernel 4: unified verify (fp64 exact) ----------------------
// One wave per query: read 64 chunk d1-keys (coalesced), fp64-rescan every
// chunk within MARGIN of the global best (always >= the winner's chunk),
// lexicographic first-min, write index + loss.
__global__ __launch_bounds__(256) void k_verify(
    const int* __restrict__ d1key,
    const double* __restrict__ enc_n, const double* __restrict__ q_s,
    const double* __restrict__ cb_n, const double* __restrict__ s_k,
    const float* __restrict__ cb, const float* __restrict__ ze,
    float* __restrict__ idx_f, int* __restrict__ idx_i,
    double* __restrict__ lossS)
{
    int tid = threadIdx.x;
    int lane = tid & 63;
    int pos = blockIdx.x*4 + (tid >> 6);

    int myk = d1key[(size_t)pos*KCHUNKS + lane];   // lane = chunk id
    int m = myk;
    #pragma unroll
    for (int off = 1; off < 64; off <<= 1) m = min(m, __shfl_xor(m, off, 64));
    float thr = __int_as_float(m & 0xFFFFFF80) + MARGIN;
    bool scan = __int_as_float(myk & 0xFFFFFF80) <= thr;
    unsigned long long mask = __ballot(scan);

    double e[DCB];
    #pragma unroll
    for (int d = 0; d < DCB; ++d) e[d] = enc_n[(size_t)pos*DCB + d];
    double qs = q_s[pos];

    double bd = 1e300; int bi = 0x7FFFFFFF;
    while (mask) {
        int c = __ffsll((long long)mask) - 1;
        mask &= mask - 1;
        #pragma unroll
        for (int r = 0; r < KCH/64; ++r) {
            int k = c*KCH + r*64 + lane;
            const double* cp = cb_n + (size_t)k*DCB;
            double dot = e[0]*cp[0] + e[1]*cp[1] + e[2]*cp[2] + e[3]*cp[3]
                       + e[4]*cp[4] + e[5]*cp[5] + e[6]*cp[6] + e[7]*cp[7];
            double dist = qs - 2.0*dot + s_k[k];
            if (dist < bd || (dist == bd && k < bi)) { bd = dist; bi = k; }
        }
    }
    #pragma unroll
    for (int off = 1; off < 64; off <<= 1) {
        double od = __shfl_xor(bd, off, 64);
        int    oi = __shfl_xor(bi, off, 64);
        if (od < bd || (od == bd && oi < bi)) { bd = od; bi = oi; }
    }
    if (lane == 0) {
        int b = pos >> 11, t = pos & (TT-1);
        idx_f[pos] = (float)bi;
        idx_i[pos] = bi;
        double ssum = 0.0;
        #pragma unroll
        for (int d = 0; d < DCB; ++d) {
            double zev = (double)ze[((size_t)b*DCB + d)*TT + t];
            double zqv = (double)cb[bi*DCB + d];
            double diff = zev - zqv;
            ssum += diff*diff;
        }
        atomicAdd(&lossS[b], ssum);
    }
}

// ---------------- kernel 5: out-projection + loss write ---------------------
__global__ __launch_bounds__(256) void k_out_proj(
    const float* __restrict__ cb, const float* __restrict__ ze,
    const int* __restrict__ idx_i, const float* __restrict__ w_out,
    const float* __restrict__ out_b, const double* __restrict__ lossS,
    float* __restrict__ zq_out, float* __restrict__ commit_out,
    float* __restrict__ cbloss_out)
{
    __shared__ float wl[128*DCB];
    __shared__ float bl[128];
    int tid = threadIdx.x;

    if (blockIdx.x == 0 && blockIdx.y == 0 && tid < BB) {
        double m = lossS[tid] / (double)(DCB*TT);
        commit_out[tid] = (float)(m * 0.005);
        cbloss_out[tid] = (float)m;
    }

    int oc = blockIdx.y;
    int obase = oc*128;
    for (int x = tid; x < 128*DCB; x += 256) wl[x] = w_out[obase*DCB + x];
    for (int x = tid; x < 128; x += 256) bl[x] = out_b[obase + x];
    __syncthreads();

    int pos = blockIdx.x*256 + tid;
    int b = pos >> 11, t = pos & (TT-1);
    int ki = idx_i[pos];
    float zq[DCB];
    #pragma unroll
    for (int d = 0; d < DCB; ++d) {
        float zev = ze[((size_t)b*DCB + d)*TT + t];
        float zqv = cb[ki*DCB + d];
        zq[d] = zev + (zqv - zev);
    }
    float* outp = zq_out + ((size_t)b*DIN + obase)*TT + t;
    for (int oo = 0; oo < 128; ++oo) {
        float acc = 0.f;
        #pragma unroll
        for (int d = 0; d < DCB; ++d) acc += wl[oo*DCB + d]*zq[d];
        acc += bl[oo];
        outp[(size_t)oo*TT] = acc;
    }
}

// ---------------- launch ----------------------------------------------------
extern "C" void kernel_launch(void* const* d_in, const int* in_sizes, int n_in,
                              void* d_out, int out_size, void* d_ws, size_t ws_size,
                              hipStream_t stream)
{
    const float* z        = (const float*)d_in[0];
    const float* in_v     = (const float*)d_in[1];
    const float* in_g     = (const float*)d_in[2];
    const float* in_b     = (const float*)d_in[3];
    const float* out_v    = (const float*)d_in[4];
    const float* out_g    = (const float*)d_in[5];
    const float* out_b    = (const float*)d_in[6];
    const float* codebook = (const float*)d_in[7];

    float* out = (float*)d_out;
    float* zq_out_p  = out + OFF_ZQOUT;
    float* commit_p  = out + OFF_COMMIT;
    float* cbloss_p  = out + OFF_CBLOSS;
    float* idx_p     = out + OFF_IDX;
    float* ze_p      = out + OFF_ZE;

    // workspace layout (doubles first)
    double* w_in_d = (double*)d_ws;                        // 8192
    double* cb_n   = w_in_d + DCB*DIN;                     // 65536
    double* s_k    = cb_n + (size_t)KK*DCB;                // 8192
    double* enc_n  = s_k + KK;                             // 131072
    double* q_s    = enc_n + (size_t)NPOS*DCB;             // 16384
    double* lossS  = q_s + NPOS;                           // 16
    float*  w_out  = (float*)(lossS + 16);                 // 8192
    float*  skp_f  = w_out + DCB*DIN;                      // 8192
    unsigned short* cb16  = (unsigned short*)(skp_f + KK); // 131072 ushorts
    unsigned short* enc16 = cb16 + (size_t)KK*16;          // 262144 ushorts
    int*    d1key  = (int*)(enc16 + (size_t)NPOS*16);      // NPOS*64 ints (4 MB)
    int*    idx_i  = d1key + (size_t)NPOS*KCHUNKS;         // 16384

    k_prep<<<44, 256, 0, stream>>>(in_v, in_g, out_v, out_g, codebook,
                                   w_in_d, w_out, cb_n, s_k, cb16, skp_f, lossS);
    k_inproj<<<NPOS/32, 256, 0, stream>>>(z, w_in_d, in_b, ze_p, enc_n, q_s, enc16);
    k_screen<<<dim3(NPOS/SCR_QB, KCHUNKS/SCR_CB), 256, 0, stream>>>(
        enc16, cb16, skp_f, d1key);
    k_verify<<<NPOS/4, 256, 0, stream>>>(d1key, enc_n, q_s, cb_n, s_k,
                                         codebook, ze_p, idx_p, idx_i, lossS);
    k_out_proj<<<dim3(NPOS/256, DIN/128), 256, 0, stream>>>(
        codebook, ze_p, idx_i, w_out, out_b, lossS,
        zq_out_p, commit_p, cbloss_p);
}

// Round 5
// 206.716 us; speedup vs baseline: 1.8706x; 1.8706x over previous
//
#include <hip/hip_runtime.h>
#include <math.h>
#include <stdint.h>

// Problem constants
#define BB    8
#define DIN   1024
#define TT    2048
#define KK    8192
#define DCB   8
#define NPOS  (BB*TT)         // 16384
#define KCHUNKS 64
#define KCH     (KK/KCHUNKS)  // 128
#define MARGIN  6e-4f         // >= 2*eps_bf16_screen(1.2e-4) + pack quant(6e-5), 2x headroom

// d_out layout (float32):
#define OFF_ZQOUT  0
#define OFF_COMMIT 16777216
#define OFF_CBLOSS 16777224
#define OFF_IDX    16777232
#define OFF_ZE     16793616

typedef short s8v __attribute__((ext_vector_type(8)));   // 8 bf16 in 4 VGPRs
typedef float f4v __attribute__((ext_vector_type(4)));

__device__ __forceinline__ unsigned short f2bf(float f) {
    unsigned u = __float_as_uint(f);
    u += 0x7FFF + ((u >> 16) & 1);          // round-to-nearest-even
    return (unsigned short)(u >> 16);
}
__device__ __forceinline__ float bf2f(unsigned short h) {
    return __uint_as_float(((unsigned)h) << 16);
}

// ---------------- kernel 1: prep (44 blocks, parallel roles) ----------------
// blocks 0..7: w_in rows (fp64); 8..11: w_out (fp32); 12..43: codebook
// (fp64 normalize + bf16 hi/lo mirror + skp).
__global__ __launch_bounds__(256) void k_prep(
    const float* __restrict__ in_v, const float* __restrict__ in_g,
    const float* __restrict__ out_v, const float* __restrict__ out_g,
    const float* __restrict__ cb,
    double* __restrict__ w_in_d, float* __restrict__ w_out_f,
    double* __restrict__ cb_n, double* __restrict__ s_k,
    unsigned short* __restrict__ cb16, float* __restrict__ skp_f)
{
    __shared__ double red[256];
    int tid = threadIdx.x;
    int blk = blockIdx.x;

    if (blk < 8) {
        int r = blk;
        double s = 0.0;
        for (int i = tid; i < DIN; i += 256) {
            double v = (double)in_v[r*DIN + i];
            s += v*v;
        }
        red[tid] = s; __syncthreads();
        for (int off = 128; off > 0; off >>= 1) {
            if (tid < off) red[tid] += red[tid+off];
            __syncthreads();
        }
        double scale = (double)in_g[r] / sqrt(red[0]);
        for (int i = tid; i < DIN; i += 256)
            w_in_d[r*DIN + i] = scale * (double)in_v[r*DIN + i];
    } else if (blk < 12) {
        int o = (blk-8)*256 + tid;
        float vv[DCB];
        double s = 0.0;
        #pragma unroll
        for (int d = 0; d < DCB; ++d) {
            vv[d] = out_v[o*DCB + d];
            s += (double)vv[d]*(double)vv[d];
        }
        double scale = (double)out_g[o] / sqrt(s);
        #pragma unroll
        for (int d = 0; d < DCB; ++d)
            w_out_f[o*DCB + d] = (float)(scale * (double)vv[d]);
    } else {
        int k = (blk-12)*256 + tid;
        double v[DCB]; double s = 0.0;
        #pragma unroll
        for (int d = 0; d < DCB; ++d) {
            v[d] = (double)cb[k*DCB + d];
            s += v[d]*v[d];
        }
        double nrm = sqrt(s);
        if (nrm < 1e-12) nrm = 1e-12;
        double s2 = 0.0;
        #pragma unroll
        for (int d = 0; d < DCB; ++d) {
            double t = v[d] / nrm;
            cb_n[(size_t)k*DCB + d] = t;
            s2 += t*t;
            float cf = (float)t;
            unsigned short bh = f2bf(cf);
            unsigned short bl = f2bf(cf - bf2f(bh));
            cb16[(size_t)k*16 + d]     = bh;
            cb16[(size_t)k*16 + 8 + d] = bl;
        }
        s_k[k] = s2;
        skp_f[k] = (float)(s2 + 4.0);   // shift => dist' = skp - 2*dot in [3,7] > 0
    }
}

// ---------------- kernel 2: fused in-projection + reduce (fp64) -------------
// Summation order identical to R1..R4 (passed) => bit-identical z_e/enc_n/q_s.
__global__ __launch_bounds__(256) void k_inproj(
    const float* __restrict__ z, const double* __restrict__ w_in_d,
    const float* __restrict__ in_b,
    float* __restrict__ ze_out, double* __restrict__ enc_n,
    double* __restrict__ q_s, unsigned short* __restrict__ enc16)
{
    __shared__ double wl[DIN*DCB];   // 64 KB
    __shared__ double red[2048];     // 16 KB

    int tid = threadIdx.x;
    for (int x = tid; x < DIN*DCB; x += 256) wl[x] = w_in_d[x];
    __syncthreads();

    int p = tid & 31;
    int q = tid >> 5;
    int pos = blockIdx.x*32 + p;
    int b = pos >> 11, t = pos & (TT-1);

    const float* zp = z + ((size_t)b*DIN + (size_t)q*128)*TT + t;
    double acc[DCB] = {0,0,0,0,0,0,0,0};
    for (int ii = 0; ii < 128; ++ii) {
        double zv = (double)zp[(size_t)ii*TT];
        int wbase = q*128 + ii;
        #pragma unroll
        for (int o = 0; o < DCB; ++o) acc[o] += wl[o*DIN + wbase] * zv;
    }
    #pragma unroll
    for (int o = 0; o < DCB; ++o) red[(q*32 + p)*DCB + o] = acc[o];
    __syncthreads();

    int p2 = tid >> 3, o2 = tid & 7;
    double s = 0.0;
    for (int q2 = 0; q2 < 8; ++q2) s += red[(q2*32 + p2)*DCB + o2];
    s += (double)in_b[o2];
    __syncthreads();
    red[p2*DCB + o2] = s;
    __syncthreads();

    if (tid < 32) {
        int pos3 = blockIdx.x*32 + tid;
        int b3 = pos3 >> 11, t3 = pos3 & (TT-1);
        double v[DCB]; double n2 = 0.0;
        #pragma unroll
        for (int o = 0; o < DCB; ++o) {
            v[o] = red[tid*DCB + o];
            n2 += v[o]*v[o];
            ze_out[((size_t)b3*DCB + o)*TT + t3] = (float)v[o];
        }
        double nrm = sqrt(n2);
        if (nrm < 1e-12) nrm = 1e-12;
        double s2 = 0.0;
        #pragma unroll
        for (int o = 0; o < DCB; ++o) {
            double e = v[o] / nrm;
            enc_n[(size_t)pos3*DCB + o] = e;
            s2 += e*e;
            float ef = (float)(-2.0 * e);      // A operand = -2*enc_n
            unsigned short ah = f2bf(ef);
            unsigned short al = f2bf(ef - bf2f(ah));
            enc16[(size_t)pos3*16 + o]     = ah;
            enc16[(size_t)pos3*16 + 8 + o] = al;
        }
        q_s[pos3] = s2;
    }
}

// ---------------- kernel 3: MFMA bf16 hi/lo argmin screen --------------------
// grid (256 q-blocks of 64, 8 chunk-groups of 8). One mfma_f32_16x16x32_bf16
// per 16q x 16n tile: K packed as A=[ah,al,ah,0] x B=[bh,bh,bl,*]
// => ah*bh + al*bh + ah*bl (residual al*bl bounded ~1.2e-4).
// skp (fp32-exact) enters via accumulator init. d1-only per chunk.
#define SCR_QB 64
#define SCR_CB 8
__global__ __launch_bounds__(256) void k_screen(
    const unsigned short* __restrict__ enc16,
    const unsigned short* __restrict__ cb16,
    const float* __restrict__ skp_f,
    int* __restrict__ d1key)   // [q][KCHUNKS]
{
    __shared__ unsigned short cbl[SCR_CB*KCH*16];  // 32 KB
    __shared__ float skl[SCR_CB*KCH];              // 4 KB
    int tid = threadIdx.x;
    int cg = blockIdx.y;

    {   // stage 8 chunks of codebook bf16 + skp
        const uint4* src = (const uint4*)(cb16 + (size_t)cg*SCR_CB*KCH*16);
        uint4* dst = (uint4*)cbl;
        for (int x = tid; x < SCR_CB*KCH*2; x += 256) dst[x] = src[x];
        const float* ss = skp_f + cg*SCR_CB*KCH;
        for (int x = tid; x < SCR_CB*KCH; x += 256) skl[x] = ss[x];
    }
    __syncthreads();

    int lane = tid & 63;
    int wv   = tid >> 6;
    int col  = lane & 15, quad = lane >> 4;
    int qbase = blockIdx.x*SCR_QB + wv*16;

    // A fragment: lane holds A[m=col][k=quad*8+j]; quad 0,2 -> ah, 1 -> al, 3 -> 0
    s8v a;
    {
        const s8v* ap = (const s8v*)(enc16 + ((size_t)(qbase + col))*16 + (quad==1 ? 8 : 0));
        a = *ap;
        if (quad == 3) { s8v zz = {0,0,0,0,0,0,0,0}; a = zz; }
    }
    int bsel = (quad == 2) ? 1 : 0;   // B: quad 0,1 -> bh, 2 -> bl, 3 -> bh (A=0 there)

    for (int c2 = 0; c2 < SCR_CB; ++c2) {
        int d0 = 0x7F800000, d1r = 0x7F800000, d2r = 0x7F800000, d3r = 0x7F800000;
        const s8v* bp = (const s8v*)(cbl + c2*KCH*16);
        const float* sp = skl + c2*KCH;
        #pragma unroll
        for (int t = 0; t < 8; ++t) {
            int n = t*16 + col;
            s8v bfr = bp[n*2 + bsel];
            float sk = sp[n];
            f4v acc = {sk, sk, sk, sk};
            acc = __builtin_amdgcn_mfma_f32_16x16x32_bf16(a, bfr, acc, 0, 0, 0);
            // C layout: col = lane&15 (n), row = quad*4 + reg  -> pack 7-bit n
            d0  = min(d0,  (int)((__float_as_uint(acc.x) & 0xFFFFFF80u) | (unsigned)n));
            d1r = min(d1r, (int)((__float_as_uint(acc.y) & 0xFFFFFF80u) | (unsigned)n));
            d2r = min(d2r, (int)((__float_as_uint(acc.z) & 0xFFFFFF80u) | (unsigned)n));
            d3r = min(d3r, (int)((__float_as_uint(acc.w) & 0xFFFFFF80u) | (unsigned)n));
        }
        // reduce over the 16 n-columns (lanes differing in low 4 bits)
        #pragma unroll
        for (int off = 1; off < 16; off <<= 1) {
            d0  = min(d0,  __shfl_xor(d0,  off, 64));
            d1r = min(d1r, __shfl_xor(d1r, off, 64));
            d2r = min(d2r, __shfl_xor(d2r, off, 64));
            d3r = min(d3r, __shfl_xor(d3r, off, 64));
        }
        if (col == 0) {
            int chunk = cg*SCR_CB + c2;
            int qrow  = qbase + quad*4;
            int* dst = d1key + (size_t)qrow*KCHUNKS + chunk;
            dst[0*KCHUNKS] = d0;
            dst[1*KCHUNKS] = d1r;
            dst[2*KCHUNKS] = d2r;
            dst[3*KCHUNKS] = d3r;
        }
    }
}

// ---------------- kernel 4: unified verify (fp64 exact, NO atomics) ---------
// One wave per query: read 64 chunk d1-keys (coalesced), fp64-rescan every
// chunk within MARGIN of the global best (always >= the winner's chunk),
// lexicographic first-min, write index + per-query loss (plain store).
__global__ __launch_bounds__(256) void k_verify(
    const int* __restrict__ d1key,
    const double* __restrict__ enc_n, const double* __restrict__ q_s,
    const double* __restrict__ cb_n, const double* __restrict__ s_k,
    const float* __restrict__ cb, const float* __restrict__ ze,
    float* __restrict__ idx_f, int* __restrict__ idx_i,
    double* __restrict__ loss_q)
{
    int tid = threadIdx.x;
    int lane = tid & 63;
    int pos = blockIdx.x*4 + (tid >> 6);

    int myk = d1key[(size_t)pos*KCHUNKS + lane];   // lane = chunk id
    int m = myk;
    #pragma unroll
    for (int off = 1; off < 64; off <<= 1) m = min(m, __shfl_xor(m, off, 64));
    float thr = __int_as_float(m & 0xFFFFFF80) + MARGIN;
    bool scan = __int_as_float(myk & 0xFFFFFF80) <= thr;
    unsigned long long mask = __ballot(scan);

    double e[DCB];
    #pragma unroll
    for (int d = 0; d < DCB; ++d) e[d] = enc_n[(size_t)pos*DCB + d];
    double qs = q_s[pos];

    double bd = 1e300; int bi = 0x7FFFFFFF;
    while (mask) {
        int c = __ffsll((long long)mask) - 1;
        mask &= mask - 1;
        #pragma unroll
        for (int r = 0; r < KCH/64; ++r) {
            int k = c*KCH + r*64 + lane;
            const double* cp = cb_n + (size_t)k*DCB;
            double dot = e[0]*cp[0] + e[1]*cp[1] + e[2]*cp[2] + e[3]*cp[3]
                       + e[4]*cp[4] + e[5]*cp[5] + e[6]*cp[6] + e[7]*cp[7];
            double dist = qs - 2.0*dot + s_k[k];
            if (dist < bd || (dist == bd && k < bi)) { bd = dist; bi = k; }
        }
    }
    #pragma unroll
    for (int off = 1; off < 64; off <<= 1) {
        double od = __shfl_xor(bd, off, 64);
        int    oi = __shfl_xor(bi, off, 64);
        if (od < bd || (od == bd && oi < bi)) { bd = od; bi = oi; }
    }
    if (lane == 0) {
        int b = pos >> 11, t = pos & (TT-1);
        idx_f[pos] = (float)bi;
        idx_i[pos] = bi;
        double ssum = 0.0;
        #pragma unroll
        for (int d = 0; d < DCB; ++d) {
            double zev = (double)ze[((size_t)b*DCB + d)*TT + t];
            double zqv = (double)cb[bi*DCB + d];
            double diff = zev - zqv;
            ssum += diff*diff;
        }
        loss_q[pos] = ssum;   // plain store; reduced by k_losses
    }
}

// ---------------- kernel 5: loss reduction (one block per batch, no atomics) -
__global__ __launch_bounds__(256) void k_losses(
    const double* __restrict__ loss_q,
    float* __restrict__ commit_out, float* __restrict__ cbloss_out)
{
    __shared__ double red[256];
    int tid = threadIdx.x;
    int b = blockIdx.x;
    double s = 0.0;
    for (int i = tid; i < TT; i += 256) s += loss_q[(size_t)b*TT + i];
    red[tid] = s; __syncthreads();
    for (int off = 128; off > 0; off >>= 1) {
        if (tid < off) red[tid] += red[tid+off];
        __syncthreads();
    }
    if (tid == 0) {
        double m = red[0] / (double)(DCB*TT);
        commit_out[b] = (float)(m * 0.005);
        cbloss_out[b] = (float)m;
    }
}

// ---------------- kernel 6: out-projection ----------------------------------
__global__ __launch_bounds__(256) void k_out_proj(
    const float* __restrict__ cb, const float* __restrict__ ze,
    const int* __restrict__ idx_i, const float* __restrict__ w_out,
    const float* __restrict__ out_b, float* __restrict__ zq_out)
{
    __shared__ float wl[128*DCB];
    __shared__ float bl[128];
    int tid = threadIdx.x;

    int oc = blockIdx.y;
    int obase = oc*128;
    for (int x = tid; x < 128*DCB; x += 256) wl[x] = w_out[obase*DCB + x];
    for (int x = tid; x < 128; x += 256) bl[x] = out_b[obase + x];
    __syncthreads();

    int pos = blockIdx.x*256 + tid;
    int b = pos >> 11, t = pos & (TT-1);
    int ki = idx_i[pos];
    float zq[DCB];
    #pragma unroll
    for (int d = 0; d < DCB; ++d) {
        float zev = ze[((size_t)b*DCB + d)*TT + t];
        float zqv = cb[ki*DCB + d];
        zq[d] = zev + (zqv - zev);
    }
    float* outp = zq_out + ((size_t)b*DIN + obase)*TT + t;
    for (int oo = 0; oo < 128; ++oo) {
        float acc = 0.f;
        #pragma unroll
        for (int d = 0; d < DCB; ++d) acc += wl[oo*DCB + d]*zq[d];
        acc += bl[oo];
        outp[(size_t)oo*TT] = acc;
    }
}

// ---------------- launch ----------------------------------------------------
extern "C" void kernel_launch(void* const* d_in, const int* in_sizes, int n_in,
                              void* d_out, int out_size, void* d_ws, size_t ws_size,
                              hipStream_t stream)
{
    const float* z        = (const float*)d_in[0];
    const float* in_v     = (const float*)d_in[1];
    const float* in_g     = (const float*)d_in[2];
    const float* in_b     = (const float*)d_in[3];
    const float* out_v    = (const float*)d_in[4];
    const float* out_g    = (const float*)d_in[5];
    const float* out_b    = (const float*)d_in[6];
    const float* codebook = (const float*)d_in[7];

    float* out = (float*)d_out;
    float* zq_out_p  = out + OFF_ZQOUT;
    float* commit_p  = out + OFF_COMMIT;
    float* cbloss_p  = out + OFF_CBLOSS;
    float* idx_p     = out + OFF_IDX;
    float* ze_p      = out + OFF_ZE;

    // workspace layout (doubles first)
    double* w_in_d = (double*)d_ws;                        // 8192
    double* cb_n   = w_in_d + DCB*DIN;                     // 65536
    double* s_k    = cb_n + (size_t)KK*DCB;                // 8192
    double* enc_n  = s_k + KK;                             // 131072
    double* q_s    = enc_n + (size_t)NPOS*DCB;             // 16384
    double* loss_q = q_s + NPOS;                           // 16384
    float*  w_out  = (float*)(loss_q + NPOS);              // 8192
    float*  skp_f  = w_out + DCB*DIN;                      // 8192
    unsigned short* cb16  = (unsigned short*)(skp_f + KK); // 131072 ushorts
    unsigned short* enc16 = cb16 + (size_t)KK*16;          // 262144 ushorts
    int*    d1key  = (int*)(enc16 + (size_t)NPOS*16);      // NPOS*64 ints (4 MB)
    int*    idx_i  = d1key + (size_t)NPOS*KCHUNKS;         // 16384

    k_prep<<<44, 256, 0, stream>>>(in_v, in_g, out_v, out_g, codebook,
                                   w_in_d, w_out, cb_n, s_k, cb16, skp_f);
    k_inproj<<<NPOS/32, 256, 0, stream>>>(z, w_in_d, in_b, ze_p, enc_n, q_s, enc16);
    k_screen<<<dim3(NPOS/SCR_QB, KCHUNKS/SCR_CB), 256, 0, stream>>>(
        enc16, cb16, skp_f, d1key);
    k_verify<<<NPOS/4, 256, 0, stream>>>(d1key, enc_n, q_s, cb_n, s_k,
                                         codebook, ze_p, idx_p, idx_i, loss_q);
    k_losses<<<BB, 256, 0, stream>>>(loss_q, commit_p, cbloss_p);
    k_out_proj<<<dim3(NPOS/256, DIN/128), 256, 0, stream>>>(
        codebook, ze_p, idx_i, w_out, out_b, zq_out_p);
}